// Round 12
// baseline (85.170 us; speedup 1.0000x reference)
//
#include <hip/hip_runtime.h>

#define S_LEN 2048
#define DMODEL 1024
#define NHEADS 16
#define WIN 256

typedef unsigned short u16;
typedef unsigned int u32;
typedef __attribute__((ext_vector_type(8))) __bf16 bf16x8;
typedef __attribute__((ext_vector_type(4))) float f32x4;
typedef __attribute__((ext_vector_type(8))) u16 u16x8;
typedef __attribute__((ext_vector_type(4))) u16 u16x4;

__device__ __forceinline__ u16 f2bf(float f) {
  u32 u = __builtin_bit_cast(u32, f);
  u += 0x7fffu + ((u >> 16) & 1u);   // round-to-nearest-even
  return (u16)(u >> 16);
}

#define GLDS16(g, l) __builtin_amdgcn_global_load_lds( \
    (const __attribute__((address_space(1))) void*)(g), \
    (__attribute__((address_space(3))) void*)(l), 16, 0, 0)

#define BAR() { asm volatile("" ::: "memory"); __builtin_amdgcn_s_barrier(); asm volatile("" ::: "memory"); }
#define VMCNT(n) asm volatile("s_waitcnt vmcnt(" #n ")" ::: "memory")

// ---------------- fused cast f32 -> bf16 (x + 4 weights, one launch) ----------------
__global__ __launch_bounds__(256) void cast_all(
    const float* __restrict__ x, const float* __restrict__ wq, const float* __restrict__ wk,
    const float* __restrict__ wv, const float* __restrict__ wo,
    u16* __restrict__ xb, u16* __restrict__ wqb, u16* __restrict__ wkb,
    u16* __restrict__ wvb, u16* __restrict__ wob) {
  const int e = (blockIdx.x * 256 + threadIdx.x) * 4;
  const float* src; u16* dst; int off;
  if (e < (1 << 22)) { src = x; dst = xb; off = e; }
  else {
    int r = e - (1 << 22);
    int seg = r >> 20; off = r & ((1 << 20) - 1);
    src = (seg == 0) ? wq : (seg == 1) ? wk : (seg == 2) ? wv : wo;
    dst = (seg == 0) ? wqb : (seg == 1) ? wkb : (seg == 2) ? wvb : wob;
  }
  float4 v = *(const float4*)(src + off);
  u16x4 o = { f2bf(v.x), f2bf(v.y), f2bf(v.z), f2bf(v.w) };
  *(u16x4*)(dst + off) = o;
}

// ---------------- NT GEMM (QKV): 128x128, BK=32, 16x16x32 MFMA, DEPTH-3 counted-vmcnt ----------------
// 3 LDS buffers; stage tile kt+3 after compute barrier; steady-state 12 loads in
// flight, gate VMCNT(8) drains exactly tile kt's 4 (tail 8->4->0).
__global__ __launch_bounds__(256) void gemm_nt(
    const u16* __restrict__ A,
    const u16* __restrict__ B0, const u16* __restrict__ B1, const u16* __restrict__ B2,
    const float* __restrict__ bias0, const float* __restrict__ bias1, const float* __restrict__ bias2,
    u16* __restrict__ C0, u16* __restrict__ C1, u16* __restrict__ C2,
    const int M, const int N, const int K)
{
  const u16* Bt; const float* bias; u16* C;
  if (blockIdx.z == 0)      { Bt = B0; bias = bias0; C = C0; }
  else if (blockIdx.z == 1) { Bt = B1; bias = bias1; C = C1; }
  else                      { Bt = B2; bias = bias2; C = C2; }

  __shared__ u16 As[3][128 * 32];   // 24 KiB
  __shared__ u16 Bs[3][128 * 32];   // 24 KiB

  const int t = threadIdx.x;
  const int row0 = blockIdx.x * 128;
  const int col0 = blockIdx.y * 128;
  const int lane = t & 63, lo = lane & 15, hi = lane >> 4;
  const int wv = t >> 6;
  const int wr = (wv >> 1) * 64, wc = (wv & 1) * 64;
  const int sx = lo & 3;

  f32x4 acc[4][4];
  #pragma unroll
  for (int i = 0; i < 4; ++i)
    #pragma unroll
    for (int j = 0; j < 4; ++j) acc[i][j] = (f32x4)0.0f;

  const int NT = K >> 5;

  auto stage = [&](int buf, int kt) {
    const int kof = kt * 32;
    #pragma unroll
    for (int c = 0; c < 2; ++c) {
      const int off = t * 16 + c * 4096;
      const int r = off >> 6;
      const int g = ((off >> 4) & 3) ^ (r & 3);
      GLDS16(A  + (size_t)(row0 + r) * K + (kof + g * 8), (u16*)As + buf * 4096 + (off >> 1));
      GLDS16(Bt + (size_t)(col0 + r) * K + (kof + g * 8), (u16*)Bs + buf * 4096 + (off >> 1));
    }
  };

  stage(0, 0);
  stage(1, 1);
  stage(2, 2);                               // 12 loads in flight
  int cur = 0;
  for (int kt = 0; kt < NT; ++kt) {
    if (kt + 2 < NT) { VMCNT(8); } else if (kt + 1 < NT) { VMCNT(4); } else { VMCNT(0); }
    BAR();                                   // tile kt fully staged for all waves
    bf16x8 af[4], bfr[4];
    #pragma unroll
    for (int mi = 0; mi < 4; ++mi) {
      const int row = wr + mi * 16 + lo;
      af[mi] = *(const bf16x8*)&As[cur][row * 32 + ((hi ^ sx) << 3)];
    }
    #pragma unroll
    for (int ni = 0; ni < 4; ++ni) {
      const int row = wc + ni * 16 + lo;
      bfr[ni] = *(const bf16x8*)&Bs[cur][row * 32 + ((hi ^ sx) << 3)];
    }
    #pragma unroll
    for (int mi = 0; mi < 4; ++mi)
      #pragma unroll
      for (int ni = 0; ni < 4; ++ni)
        acc[mi][ni] = __builtin_amdgcn_mfma_f32_16x16x32_bf16(af[mi], bfr[ni], acc[mi][ni], 0, 0, 0);
    BAR();                                   // all waves done reading buf[cur]
    if (kt + 3 < NT) stage(cur, kt + 3);     // restage freed buffer
    cur = (cur == 2) ? 0 : cur + 1;
  }

  #pragma unroll
  for (int mi = 0; mi < 4; ++mi) {
    #pragma unroll
    for (int ni = 0; ni < 4; ++ni) {
      const int col = col0 + wc + ni * 16 + lo;
      const float bv = bias[col];
      #pragma unroll
      for (int r = 0; r < 4; ++r) {
        const int row = row0 + wr + mi * 16 + hi * 4 + r;
        C[(size_t)row * N + col] = f2bf(acc[mi][ni][r] + bv);
      }
    }
  }
}

// ---------------- out-proj NT GEMM: 128x64, BK=32, DEPTH-3 counted-vmcnt ----------------
__global__ __launch_bounds__(256) void gemm_out64(
    const u16* __restrict__ A, const u16* __restrict__ Bt,
    const float* __restrict__ bias, float* __restrict__ C)
{
  constexpr int N = 1024, K = 1024;

  __shared__ u16 As[3][128 * 32];
  __shared__ u16 Bs[3][64 * 32];

  int id = blockIdx.y * gridDim.x + blockIdx.x;      // 0..511
  int wgid = (id & 7) * 64 + (id >> 3);
  const int row0 = (wgid >> 4) * 128;
  const int col0 = (wgid & 15) * 64;

  const int t = threadIdx.x;
  const int lane = t & 63, lo = lane & 15, hi = lane >> 4;
  const int wv = t >> 6;
  const int wr = (wv >> 1) * 64, wc = (wv & 1) * 32;
  const int sx = lo & 3;

  f32x4 acc[4][2];
  #pragma unroll
  for (int i = 0; i < 4; ++i)
    #pragma unroll
    for (int j = 0; j < 2; ++j) acc[i][j] = (f32x4)0.0f;

  auto stage = [&](int buf, int kt) {
    const int kof = kt * 32;
    #pragma unroll
    for (int c = 0; c < 2; ++c) {
      const int off = t * 16 + c * 4096;
      const int r = off >> 6;
      const int g = ((off >> 4) & 3) ^ (r & 3);
      GLDS16(A + (size_t)(row0 + r) * K + (kof + g * 8), (u16*)As + buf * 4096 + (off >> 1));
    }
    {
      const int off = t * 16;
      const int r = off >> 6;
      const int g = ((off >> 4) & 3) ^ (r & 3);
      GLDS16(Bt + (size_t)(col0 + r) * K + (kof + g * 8), (u16*)Bs + buf * 2048 + (off >> 1));
    }
  };

  stage(0, 0);
  stage(1, 1);
  stage(2, 2);                               // 9 loads in flight
  int cur = 0;
  for (int kt = 0; kt < (K >> 5); ++kt) {
    if (kt + 2 < (K >> 5)) { VMCNT(6); } else if (kt + 1 < (K >> 5)) { VMCNT(3); } else { VMCNT(0); }
    BAR();
    bf16x8 af[4], bfr[2];
    #pragma unroll
    for (int mi = 0; mi < 4; ++mi) {
      const int row = wr + mi * 16 + lo;
      af[mi] = *(const bf16x8*)&As[cur][row * 32 + ((hi ^ sx) << 3)];
    }
    #pragma unroll
    for (int ni = 0; ni < 2; ++ni) {
      const int row = wc + ni * 16 + lo;
      bfr[ni] = *(const bf16x8*)&Bs[cur][row * 32 + ((hi ^ sx) << 3)];
    }
    #pragma unroll
    for (int mi = 0; mi < 4; ++mi)
      #pragma unroll
      for (int ni = 0; ni < 2; ++ni)
        acc[mi][ni] = __builtin_amdgcn_mfma_f32_16x16x32_bf16(af[mi], bfr[ni], acc[mi][ni], 0, 0, 0);
    BAR();
    if (kt + 3 < (K >> 5)) stage(cur, kt + 3);
    cur = (cur == 2) ? 0 : cur + 1;
  }

  #pragma unroll
  for (int mi = 0; mi < 4; ++mi) {
    #pragma unroll
    for (int ni = 0; ni < 2; ++ni) {
      const int col = col0 + wc + ni * 16 + lo;
      const float bv = bias[col];
      #pragma unroll
      for (int r = 0; r < 4; ++r) {
        const int row = row0 + wr + mi * 16 + hi * 4 + r;
        C[(size_t)row * N + col] = acc[mi][ni][r] + bv;
      }
    }
  }
}

// ---------------- windowed causal attention: QBLK=128, 8 waves, static-max softmax (R9) ----------------
__device__ __forceinline__ int swzK(int row, int col) {   // K/P tiles
  int byte = (row << 7) + (col << 1);
  byte ^= (row & 7) << 4;
  return byte >> 1;
}
__device__ __forceinline__ int swzV(int d, int j) {       // Vt tile (row=d, col=j)
  int byte = (d << 7) + (j << 1);
  byte ^= ((d & 7) << 4) ^ (((d >> 4) & 3) << 5);
  return byte >> 1;
}

__global__ __launch_bounds__(512) void attn_win(const u16* __restrict__ Q,
                                                const u16* __restrict__ K,
                                                const u16* __restrict__ V,
                                                u16* __restrict__ O) {
  const int qt = blockIdx.x, h = blockIdx.y, b = blockIdx.z;
  const int q0 = qt * 128;
  const int t = threadIdx.x;
  const int wv = t >> 6, lane = t & 63, lo = lane & 15, hi = lane >> 4;

  __shared__ u16 Ks[2][64 * 64];
  __shared__ u16 Vt[2][64 * 64];
  __shared__ u16 Ps[8][16 * 64];

  const size_t base = ((size_t)b * S_LEN) * DMODEL + h * 64;
  const int w0 = q0 + wv * 16;          // this wave's 16-row strip

  // Q direct global->regs, pre-scaled by 1/8 (exact in bf16: exponent-only)
  bf16x8 qf[2];
  {
    const u16* qp = Q + base + (size_t)(w0 + lo) * DMODEL;
    u16x8 qa = *(const u16x8*)(qp + hi * 8);
    u16x8 qb = *(const u16x8*)(qp + 32 + hi * 8);
    union { u16x8 s; bf16x8 v; } ua, ub;
    #pragma unroll
    for (int e = 0; e < 8; ++e) {
      float fa = __builtin_bit_cast(float, (u32)qa[e] << 16) * 0.125f;
      float fb = __builtin_bit_cast(float, (u32)qb[e] << 16) * 0.125f;
      ua.s[e] = (u16)(__builtin_bit_cast(u32, fa) >> 16);
      ub.s[e] = (u16)(__builtin_bit_cast(u32, fb) >> 16);
    }
    qf[0] = ua.v; qf[1] = ub.v;
  }

  const int vrow = t >> 3;              // j in chunk (0..63)
  const int vc0  = (t & 7) * 8;         // d group (0..56)
  const int ktmin = max(0, (256 - q0) >> 6);

  u16x8 kra, vra;
  auto issue = [&](int kt) {
    const int jg = q0 - 256 + kt * 64 + vrow;
    if (jg >= 0) {
      kra = *(const u16x8*)(K + base + (size_t)jg * DMODEL + vc0);
      vra = *(const u16x8*)(V + base + (size_t)jg * DMODEL + vc0);
    } else { kra = (u16x8)0; vra = (u16x8)0; }
  };
  auto commit = [&](int buf) {
    *(u16x8*)&Ks[buf][swzK(vrow, vc0)] = kra;
    #pragma unroll
    for (int e = 0; e < 8; ++e)
      Vt[buf][swzV(vc0 + e, vrow)] = vra[e];
  };

  issue(ktmin);
  commit(0);
  __syncthreads();

  f32x4 oacc[4];
  #pragma unroll
  for (int i = 0; i < 4; ++i) oacc[i] = (f32x4)0.0f;
  float l_r[4] = {0.f, 0.f, 0.f, 0.f};

  int cur = 0;
  for (int kt = ktmin; kt < 6; ++kt) {
    const int kstart = q0 - 256 + kt * 64;
    if (kt < 5) issue(kt + 1);           // T14: next chunk's loads in flight

    const bool act = (kstart <= w0 + 15) && (kstart + 63 >= w0 - 255);
    if (act) {
      f32x4 sfr[4];
      #pragma unroll
      for (int ni = 0; ni < 4; ++ni) {
        sfr[ni] = (f32x4)0.0f;
        #pragma unroll
        for (int kq = 0; kq < 2; ++kq) {
          bf16x8 kf = *(const bf16x8*)&Ks[cur][swzK(ni * 16 + lo, kq * 32 + hi * 8)];
          sfr[ni] = __builtin_amdgcn_mfma_f32_16x16x32_bf16(qf[kq], kf, sfr[ni], 0, 0, 0);
        }
      }

      const int i0 = w0 + hi * 4;
      float pr[4][4];
      #pragma unroll
      for (int ni = 0; ni < 4; ++ni) {
        const int j = kstart + ni * 16 + lo;
        #pragma unroll
        for (int r = 0; r < 4; ++r) {
          const int i = i0 + r;
          const bool ok = (j >= 0) & (j <= i) & (i - j < WIN);
          const float x = ok ? sfr[ni][r] : -1e30f;
          const float p = __expf(x);     // exp(-1e30) == 0 -> masked entries vanish
          pr[ni][r] = p;
          l_r[r] += p;
        }
      }

      #pragma unroll
      for (int ni = 0; ni < 4; ++ni)
        #pragma unroll
        for (int r = 0; r < 4; ++r)
          Ps[wv][swzK(hi * 4 + r, ni * 16 + lo)] = f2bf(pr[ni][r]);

      bf16x8 pa[2];
      #pragma unroll
      for (int kp = 0; kp < 2; ++kp)
        pa[kp] = *(const bf16x8*)&Ps[wv][swzK(lo, kp * 32 + hi * 8)];

      #pragma unroll
      for (int ni = 0; ni < 4; ++ni) {
        #pragma unroll
        for (int kp = 0; kp < 2; ++kp) {
          bf16x8 vf = *(const bf16x8*)&Vt[cur][swzV(ni * 16 + lo, kp * 32 + hi * 8)];
          oacc[ni] = __builtin_amdgcn_mfma_f32_16x16x32_bf16(pa[kp], vf, oacc[ni], 0, 0, 0);
        }
      }
    }

    if (kt < 5) commit(cur ^ 1);         // vmcnt wait lands here, writes buf^1
    __syncthreads();                      // one barrier per chunk
    cur ^= 1;
  }

  #pragma unroll
  for (int d = 1; d < 16; d <<= 1) {
    #pragma unroll
    for (int r = 0; r < 4; ++r) l_r[r] += __shfl_xor(l_r[r], d);
  }

  #pragma unroll
  for (int r = 0; r < 4; ++r) {
    const float inv = 1.0f / l_r[r];
    const int row = w0 + hi * 4 + r;
    #pragma unroll
    for (int ni = 0; ni < 4; ++ni)
      O[base + (size_t)row * DMODEL + ni * 16 + lo] = f2bf(oacc[ni][r] * inv);
  }
}

// ---------------- launch ----------------
extern "C" void kernel_launch(void* const* d_in, const int* in_sizes, int n_in,
                              void* d_out, int out_size, void* d_ws, size_t ws_size,
                              hipStream_t stream) {
  const float* x  = (const float*)d_in[0];
  const float* wq = (const float*)d_in[1];
  const float* bq = (const float*)d_in[2];
  const float* wk = (const float*)d_in[3];
  const float* bk = (const float*)d_in[4];
  const float* wvp = (const float*)d_in[5];
  const float* bv = (const float*)d_in[6];
  const float* wo = (const float*)d_in[7];
  const float* bo = (const float*)d_in[8];
  float* out = (float*)d_out;

  char* ws = (char*)d_ws;
  const size_t MB = 1024 * 1024;
  u16* xb  = (u16*)(ws);
  u16* wqb = (u16*)(ws + 8 * MB);
  u16* wkb = (u16*)(ws + 10 * MB);
  u16* wvb = (u16*)(ws + 12 * MB);
  u16* wob = (u16*)(ws + 14 * MB);
  u16* Qb  = (u16*)(ws + 16 * MB);
  u16* Kb  = (u16*)(ws + 24 * MB);
  u16* Vb  = (u16*)(ws + 32 * MB);
  u16* Ob  = (u16*)(ws + 40 * MB);   // ends at 48 MB

  cast_all<<<8192, 256, 0, stream>>>(x, wq, wk, wvp, wo, xb, wqb, wkb, wvb, wob);

  dim3 g1(4096 / 128, 1024 / 128, 3);
  gemm_nt<<<g1, 256, 0, stream>>>(xb, wqb, wkb, wvb, bq, bk, bv,
                                  Qb, Kb, Vb, 4096, 1024, 1024);

  attn_win<<<dim3(S_LEN / 128, NHEADS, 2), 512, 0, stream>>>(Qb, Kb, Vb, Ob);

  gemm_out64<<<dim3(32, 16), 256, 0, stream>>>(Ob, wob, bo, out);
}

// Round 13
// 85.033 us; speedup vs baseline: 1.0016x; 1.0016x over previous
//
#include <hip/hip_runtime.h>

#define S_LEN 2048
#define DMODEL 1024
#define NHEADS 16
#define WIN 256

typedef unsigned short u16;
typedef unsigned int u32;
typedef __attribute__((ext_vector_type(8))) __bf16 bf16x8;
typedef __attribute__((ext_vector_type(4))) float f32x4;
typedef __attribute__((ext_vector_type(8))) u16 u16x8;
typedef __attribute__((ext_vector_type(4))) u16 u16x4;

__device__ __forceinline__ u16 f2bf(float f) {
  u32 u = __builtin_bit_cast(u32, f);
  u += 0x7fffu + ((u >> 16) & 1u);   // round-to-nearest-even
  return (u16)(u >> 16);
}

#define GLDS16(g, l) __builtin_amdgcn_global_load_lds( \
    (const __attribute__((address_space(1))) void*)(g), \
    (__attribute__((address_space(3))) void*)(l), 16, 0, 0)

#define BAR() { asm volatile("" ::: "memory"); __builtin_amdgcn_s_barrier(); asm volatile("" ::: "memory"); }
#define VMCNT(n) asm volatile("s_waitcnt vmcnt(" #n ")" ::: "memory")

// ---------------- fused cast f32 -> bf16 (x + 4 weights, one launch) ----------------
__global__ __launch_bounds__(256) void cast_all(
    const float* __restrict__ x, const float* __restrict__ wq, const float* __restrict__ wk,
    const float* __restrict__ wv, const float* __restrict__ wo,
    u16* __restrict__ xb, u16* __restrict__ wqb, u16* __restrict__ wkb,
    u16* __restrict__ wvb, u16* __restrict__ wob) {
  const int e = (blockIdx.x * 256 + threadIdx.x) * 4;
  const float* src; u16* dst; int off;
  if (e < (1 << 22)) { src = x; dst = xb; off = e; }
  else {
    int r = e - (1 << 22);
    int seg = r >> 20; off = r & ((1 << 20) - 1);
    src = (seg == 0) ? wq : (seg == 1) ? wk : (seg == 2) ? wv : wo;
    dst = (seg == 0) ? wqb : (seg == 1) ? wkb : (seg == 2) ? wvb : wob;
  }
  float4 v = *(const float4*)(src + off);
  u16x4 o = { f2bf(v.x), f2bf(v.y), f2bf(v.z), f2bf(v.w) };
  *(u16x4*)(dst + off) = o;
}

// ---------------- NT GEMM (QKV): 128x128, BK=32, 3-buffer rotation, ONE barrier/K-tile ----------------
// Per K-tile: VMCNT(4) [drain tile kt] -> BAR -> stage tile kt+2 into buffer
// (kt-1)%3 (quiescent: read finished last iter, proven by the barrier) ->
// swizzled ds_read + 16 MFMA. Prologue stages tiles 0,1. Tail gate VMCNT(0).
__global__ __launch_bounds__(256) void gemm_nt(
    const u16* __restrict__ A,
    const u16* __restrict__ B0, const u16* __restrict__ B1, const u16* __restrict__ B2,
    const float* __restrict__ bias0, const float* __restrict__ bias1, const float* __restrict__ bias2,
    u16* __restrict__ C0, u16* __restrict__ C1, u16* __restrict__ C2,
    const int M, const int N, const int K)
{
  const u16* Bt; const float* bias; u16* C;
  if (blockIdx.z == 0)      { Bt = B0; bias = bias0; C = C0; }
  else if (blockIdx.z == 1) { Bt = B1; bias = bias1; C = C1; }
  else                      { Bt = B2; bias = bias2; C = C2; }

  __shared__ u16 As[3][128 * 32];   // 24 KiB
  __shared__ u16 Bs[3][128 * 32];   // 24 KiB

  const int t = threadIdx.x;
  const int row0 = blockIdx.x * 128;
  const int col0 = blockIdx.y * 128;
  const int lane = t & 63, lo = lane & 15, hi = lane >> 4;
  const int wv = t >> 6;
  const int wr = (wv >> 1) * 64, wc = (wv & 1) * 64;
  const int sx = lo & 3;

  f32x4 acc[4][4];
  #pragma unroll
  for (int i = 0; i < 4; ++i)
    #pragma unroll
    for (int j = 0; j < 4; ++j) acc[i][j] = (f32x4)0.0f;

  const int NT = K >> 5;

  auto stage = [&](int buf, int kt) {
    const int kof = kt * 32;
    #pragma unroll
    for (int c = 0; c < 2; ++c) {
      const int off = t * 16 + c * 4096;
      const int r = off >> 6;
      const int g = ((off >> 4) & 3) ^ (r & 3);
      GLDS16(A  + (size_t)(row0 + r) * K + (kof + g * 8), (u16*)As + buf * 4096 + (off >> 1));
      GLDS16(Bt + (size_t)(col0 + r) * K + (kof + g * 8), (u16*)Bs + buf * 4096 + (off >> 1));
    }
  };

  stage(0, 0);
  stage(1, 1);                               // 8 loads in flight
  int cur = 0;
  for (int kt = 0; kt < NT; ++kt) {
    if (kt + 1 < NT) { VMCNT(4); } else { VMCNT(0); }
    BAR();                                   // tile kt staged for all waves; tile kt-1 reads quiescent
    if (kt + 2 < NT) stage((cur + 2) % 3, kt + 2);   // restage the buffer freed last iter
    bf16x8 af[4], bfr[4];
    #pragma unroll
    for (int mi = 0; mi < 4; ++mi) {
      const int row = wr + mi * 16 + lo;
      af[mi] = *(const bf16x8*)&As[cur][row * 32 + ((hi ^ sx) << 3)];
    }
    #pragma unroll
    for (int ni = 0; ni < 4; ++ni) {
      const int row = wc + ni * 16 + lo;
      bfr[ni] = *(const bf16x8*)&Bs[cur][row * 32 + ((hi ^ sx) << 3)];
    }
    #pragma unroll
    for (int mi = 0; mi < 4; ++mi)
      #pragma unroll
      for (int ni = 0; ni < 4; ++ni)
        acc[mi][ni] = __builtin_amdgcn_mfma_f32_16x16x32_bf16(af[mi], bfr[ni], acc[mi][ni], 0, 0, 0);
    cur = (cur == 2) ? 0 : cur + 1;
  }

  #pragma unroll
  for (int mi = 0; mi < 4; ++mi) {
    #pragma unroll
    for (int ni = 0; ni < 4; ++ni) {
      const int col = col0 + wc + ni * 16 + lo;
      const float bv = bias[col];
      #pragma unroll
      for (int r = 0; r < 4; ++r) {
        const int row = row0 + wr + mi * 16 + hi * 4 + r;
        C[(size_t)row * N + col] = f2bf(acc[mi][ni][r] + bv);
      }
    }
  }
}

// ---------------- out-proj NT GEMM: 128x64, BK=32, 3-buffer rotation, ONE barrier/K-tile ----------------
__global__ __launch_bounds__(256) void gemm_out64(
    const u16* __restrict__ A, const u16* __restrict__ Bt,
    const float* __restrict__ bias, float* __restrict__ C)
{
  constexpr int N = 1024, K = 1024;

  __shared__ u16 As[3][128 * 32];
  __shared__ u16 Bs[3][64 * 32];

  int id = blockIdx.y * gridDim.x + blockIdx.x;      // 0..511
  int wgid = (id & 7) * 64 + (id >> 3);
  const int row0 = (wgid >> 4) * 128;
  const int col0 = (wgid & 15) * 64;

  const int t = threadIdx.x;
  const int lane = t & 63, lo = lane & 15, hi = lane >> 4;
  const int wv = t >> 6;
  const int wr = (wv >> 1) * 64, wc = (wv & 1) * 32;
  const int sx = lo & 3;

  f32x4 acc[4][2];
  #pragma unroll
  for (int i = 0; i < 4; ++i)
    #pragma unroll
    for (int j = 0; j < 2; ++j) acc[i][j] = (f32x4)0.0f;

  auto stage = [&](int buf, int kt) {
    const int kof = kt * 32;
    #pragma unroll
    for (int c = 0; c < 2; ++c) {
      const int off = t * 16 + c * 4096;
      const int r = off >> 6;
      const int g = ((off >> 4) & 3) ^ (r & 3);
      GLDS16(A + (size_t)(row0 + r) * K + (kof + g * 8), (u16*)As + buf * 4096 + (off >> 1));
    }
    {
      const int off = t * 16;
      const int r = off >> 6;
      const int g = ((off >> 4) & 3) ^ (r & 3);
      GLDS16(Bt + (size_t)(col0 + r) * K + (kof + g * 8), (u16*)Bs + buf * 2048 + (off >> 1));
    }
  };

  stage(0, 0);
  stage(1, 1);                                // 6 loads in flight
  int cur = 0;
  for (int kt = 0; kt < (K >> 5); ++kt) {
    if (kt + 1 < (K >> 5)) { VMCNT(3); } else { VMCNT(0); }
    BAR();
    if (kt + 2 < (K >> 5)) stage((cur + 2) % 3, kt + 2);
    bf16x8 af[4], bfr[2];
    #pragma unroll
    for (int mi = 0; mi < 4; ++mi) {
      const int row = wr + mi * 16 + lo;
      af[mi] = *(const bf16x8*)&As[cur][row * 32 + ((hi ^ sx) << 3)];
    }
    #pragma unroll
    for (int ni = 0; ni < 2; ++ni) {
      const int row = wc + ni * 16 + lo;
      bfr[ni] = *(const bf16x8*)&Bs[cur][row * 32 + ((hi ^ sx) << 3)];
    }
    #pragma unroll
    for (int mi = 0; mi < 4; ++mi)
      #pragma unroll
      for (int ni = 0; ni < 2; ++ni)
        acc[mi][ni] = __builtin_amdgcn_mfma_f32_16x16x32_bf16(af[mi], bfr[ni], acc[mi][ni], 0, 0, 0);
    cur = (cur == 2) ? 0 : cur + 1;
  }

  #pragma unroll
  for (int mi = 0; mi < 4; ++mi) {
    #pragma unroll
    for (int ni = 0; ni < 2; ++ni) {
      const int col = col0 + wc + ni * 16 + lo;
      const float bv = bias[col];
      #pragma unroll
      for (int r = 0; r < 4; ++r) {
        const int row = row0 + wr + mi * 16 + hi * 4 + r;
        C[(size_t)row * N + col] = acc[mi][ni][r] + bv;
      }
    }
  }
}

// ---------------- windowed causal attention: QBLK=128, 8 waves, static-max softmax (R9) ----------------
__device__ __forceinline__ int swzK(int row, int col) {   // K/P tiles
  int byte = (row << 7) + (col << 1);
  byte ^= (row & 7) << 4;
  return byte >> 1;
}
__device__ __forceinline__ int swzV(int d, int j) {       // Vt tile (row=d, col=j)
  int byte = (d << 7) + (j << 1);
  byte ^= ((d & 7) << 4) ^ (((d >> 4) & 3) << 5);
  return byte >> 1;
}

__global__ __launch_bounds__(512) void attn_win(const u16* __restrict__ Q,
                                                const u16* __restrict__ K,
                                                const u16* __restrict__ V,
                                                u16* __restrict__ O) {
  const int qt = blockIdx.x, h = blockIdx.y, b = blockIdx.z;
  const int q0 = qt * 128;
  const int t = threadIdx.x;
  const int wv = t >> 6, lane = t & 63, lo = lane & 15, hi = lane >> 4;

  __shared__ u16 Ks[2][64 * 64];
  __shared__ u16 Vt[2][64 * 64];
  __shared__ u16 Ps[8][16 * 64];

  const size_t base = ((size_t)b * S_LEN) * DMODEL + h * 64;
  const int w0 = q0 + wv * 16;          // this wave's 16-row strip

  // Q direct global->regs, pre-scaled by 1/8 (exact in bf16: exponent-only)
  bf16x8 qf[2];
  {
    const u16* qp = Q + base + (size_t)(w0 + lo) * DMODEL;
    u16x8 qa = *(const u16x8*)(qp + hi * 8);
    u16x8 qb = *(const u16x8*)(qp + 32 + hi * 8);
    union { u16x8 s; bf16x8 v; } ua, ub;
    #pragma unroll
    for (int e = 0; e < 8; ++e) {
      float fa = __builtin_bit_cast(float, (u32)qa[e] << 16) * 0.125f;
      float fb = __builtin_bit_cast(float, (u32)qb[e] << 16) * 0.125f;
      ua.s[e] = (u16)(__builtin_bit_cast(u32, fa) >> 16);
      ub.s[e] = (u16)(__builtin_bit_cast(u32, fb) >> 16);
    }
    qf[0] = ua.v; qf[1] = ub.v;
  }

  const int vrow = t >> 3;              // j in chunk (0..63)
  const int vc0  = (t & 7) * 8;         // d group (0..56)
  const int ktmin = max(0, (256 - q0) >> 6);

  u16x8 kra, vra;
  auto issue = [&](int kt) {
    const int jg = q0 - 256 + kt * 64 + vrow;
    if (jg >= 0) {
      kra = *(const u16x8*)(K + base + (size_t)jg * DMODEL + vc0);
      vra = *(const u16x8*)(V + base + (size_t)jg * DMODEL + vc0);
    } else { kra = (u16x8)0; vra = (u16x8)0; }
  };
  auto commit = [&](int buf) {
    *(u16x8*)&Ks[buf][swzK(vrow, vc0)] = kra;
    #pragma unroll
    for (int e = 0; e < 8; ++e)
      Vt[buf][swzV(vc0 + e, vrow)] = vra[e];
  };

  issue(ktmin);
  commit(0);
  __syncthreads();

  f32x4 oacc[4];
  #pragma unroll
  for (int i = 0; i < 4; ++i) oacc[i] = (f32x4)0.0f;
  float l_r[4] = {0.f, 0.f, 0.f, 0.f};

  int cur = 0;
  for (int kt = ktmin; kt < 6; ++kt) {
    const int kstart = q0 - 256 + kt * 64;
    if (kt < 5) issue(kt + 1);           // T14: next chunk's loads in flight

    const bool act = (kstart <= w0 + 15) && (kstart + 63 >= w0 - 255);
    if (act) {
      f32x4 sfr[4];
      #pragma unroll
      for (int ni = 0; ni < 4; ++ni) {
        sfr[ni] = (f32x4)0.0f;
        #pragma unroll
        for (int kq = 0; kq < 2; ++kq) {
          bf16x8 kf = *(const bf16x8*)&Ks[cur][swzK(ni * 16 + lo, kq * 32 + hi * 8)];
          sfr[ni] = __builtin_amdgcn_mfma_f32_16x16x32_bf16(qf[kq], kf, sfr[ni], 0, 0, 0);
        }
      }

      const int i0 = w0 + hi * 4;
      float pr[4][4];
      #pragma unroll
      for (int ni = 0; ni < 4; ++ni) {
        const int j = kstart + ni * 16 + lo;
        #pragma unroll
        for (int r = 0; r < 4; ++r) {
          const int i = i0 + r;
          const bool ok = (j >= 0) & (j <= i) & (i - j < WIN);
          const float x = ok ? sfr[ni][r] : -1e30f;
          const float p = __expf(x);     // exp(-1e30) == 0 -> masked entries vanish
          pr[ni][r] = p;
          l_r[r] += p;
        }
      }

      #pragma unroll
      for (int ni = 0; ni < 4; ++ni)
        #pragma unroll
        for (int r = 0; r < 4; ++r)
          Ps[wv][swzK(hi * 4 + r, ni * 16 + lo)] = f2bf(pr[ni][r]);

      bf16x8 pa[2];
      #pragma unroll
      for (int kp = 0; kp < 2; ++kp)
        pa[kp] = *(const bf16x8*)&Ps[wv][swzK(lo, kp * 32 + hi * 8)];

      #pragma unroll
      for (int ni = 0; ni < 4; ++ni) {
        #pragma unroll
        for (int kp = 0; kp < 2; ++kp) {
          bf16x8 vf = *(const bf16x8*)&Vt[cur][swzV(ni * 16 + lo, kp * 32 + hi * 8)];
          oacc[ni] = __builtin_amdgcn_mfma_f32_16x16x32_bf16(pa[kp], vf, oacc[ni], 0, 0, 0);
        }
      }
    }

    if (kt < 5) commit(cur ^ 1);         // vmcnt wait lands here, writes buf^1
    __syncthreads();                      // one barrier per chunk
    cur ^= 1;
  }

  #pragma unroll
  for (int d = 1; d < 16; d <<= 1) {
    #pragma unroll
    for (int r = 0; r < 4; ++r) l_r[r] += __shfl_xor(l_r[r], d);
  }

  #pragma unroll
  for (int r = 0; r < 4; ++r) {
    const float inv = 1.0f / l_r[r];
    const int row = w0 + hi * 4 + r;
    #pragma unroll
    for (int ni = 0; ni < 4; ++ni)
      O[base + (size_t)row * DMODEL + ni * 16 + lo] = f2bf(oacc[ni][r] * inv);
  }
}

// ---------------- launch ----------------
extern "C" void kernel_launch(void* const* d_in, const int* in_sizes, int n_in,
                              void* d_out, int out_size, void* d_ws, size_t ws_size,
                              hipStream_t stream) {
  const float* x  = (const float*)d_in[0];
  const float* wq = (const float*)d_in[1];
  const float* bq = (const float*)d_in[2];
  const float* wk = (const float*)d_in[3];
  const float* bk = (const float*)d_in[4];
  const float* wvp = (const float*)d_in[5];
  const float* bv = (const float*)d_in[6];
  const float* wo = (const float*)d_in[7];
  const float* bo = (const float*)d_in[8];
  float* out = (float*)d_out;

  char* ws = (char*)d_ws;
  const size_t MB = 1024 * 1024;
  u16* xb  = (u16*)(ws);
  u16* wqb = (u16*)(ws + 8 * MB);
  u16* wkb = (u16*)(ws + 10 * MB);
  u16* wvb = (u16*)(ws + 12 * MB);
  u16* wob = (u16*)(ws + 14 * MB);
  u16* Qb  = (u16*)(ws + 16 * MB);
  u16* Kb  = (u16*)(ws + 24 * MB);
  u16* Vb  = (u16*)(ws + 32 * MB);
  u16* Ob  = (u16*)(ws + 40 * MB);   // ends at 48 MB

  cast_all<<<8192, 256, 0, stream>>>(x, wq, wk, wvp, wo, xb, wqb, wkb, wvb, wob);

  dim3 g1(4096 / 128, 1024 / 128, 3);
  gemm_nt<<<g1, 256, 0, stream>>>(xb, wqb, wkb, wvb, bq, bk, bv,
                                  Qb, Kb, Vb, 4096, 1024, 1024);

  attn_win<<<dim3(S_LEN / 128, NHEADS, 2), 512, 0, stream>>>(Qb, Kb, Vb, Ob);

  gemm_out64<<<dim3(32, 16), 256, 0, stream>>>(Ob, wob, bo, out);
}

// Round 14
// 81.064 us; speedup vs baseline: 1.0507x; 1.0490x over previous
//
#include <hip/hip_runtime.h>

#define S_LEN 2048
#define DMODEL 1024
#define NHEADS 16
#define WIN 256

typedef unsigned short u16;
typedef unsigned int u32;
typedef __attribute__((ext_vector_type(8))) __bf16 bf16x8;
typedef __attribute__((ext_vector_type(4))) float f32x4;
typedef __attribute__((ext_vector_type(8))) u16 u16x8;
typedef __attribute__((ext_vector_type(4))) u16 u16x4;

__device__ __forceinline__ u16 f2bf(float f) {
  u32 u = __builtin_bit_cast(u32, f);
  u += 0x7fffu + ((u >> 16) & 1u);   // round-to-nearest-even
  return (u16)(u >> 16);
}

#define GLDS16(g, l) __builtin_amdgcn_global_load_lds( \
    (const __attribute__((address_space(1))) void*)(g), \
    (__attribute__((address_space(3))) void*)(l), 16, 0, 0)

#define BAR() { asm volatile("" ::: "memory"); __builtin_amdgcn_s_barrier(); asm volatile("" ::: "memory"); }
#define VMCNT(n) asm volatile("s_waitcnt vmcnt(" #n ")" ::: "memory")

// ---------------- fused cast f32 -> bf16 (x + 4 weights, one launch) ----------------
__global__ __launch_bounds__(256) void cast_all(
    const float* __restrict__ x, const float* __restrict__ wq, const float* __restrict__ wk,
    const float* __restrict__ wv, const float* __restrict__ wo,
    u16* __restrict__ xb, u16* __restrict__ wqb, u16* __restrict__ wkb,
    u16* __restrict__ wvb, u16* __restrict__ wob) {
  const int e = (blockIdx.x * 256 + threadIdx.x) * 4;
  const float* src; u16* dst; int off;
  if (e < (1 << 22)) { src = x; dst = xb; off = e; }
  else {
    int r = e - (1 << 22);
    int seg = r >> 20; off = r & ((1 << 20) - 1);
    src = (seg == 0) ? wq : (seg == 1) ? wk : (seg == 2) ? wv : wo;
    dst = (seg == 0) ? wqb : (seg == 1) ? wkb : (seg == 2) ? wvb : wob;
  }
  float4 v = *(const float4*)(src + off);
  u16x4 o = { f2bf(v.x), f2bf(v.y), f2bf(v.z), f2bf(v.w) };
  *(u16x4*)(dst + off) = o;
}

// ---------------- NT GEMM (QKV): 128x128, BK=32, counted-vmcnt 2-phase (R9 best) ----------------
__global__ __launch_bounds__(256) void gemm_nt(
    const u16* __restrict__ A,
    const u16* __restrict__ B0, const u16* __restrict__ B1, const u16* __restrict__ B2,
    const float* __restrict__ bias0, const float* __restrict__ bias1, const float* __restrict__ bias2,
    u16* __restrict__ C0, u16* __restrict__ C1, u16* __restrict__ C2,
    const int M, const int N, const int K)
{
  const u16* Bt; const float* bias; u16* C;
  if (blockIdx.z == 0)      { Bt = B0; bias = bias0; C = C0; }
  else if (blockIdx.z == 1) { Bt = B1; bias = bias1; C = C1; }
  else                      { Bt = B2; bias = bias2; C = C2; }

  __shared__ u16 As[2][128 * 32];
  __shared__ u16 Bs[2][128 * 32];

  const int t = threadIdx.x;
  const int row0 = blockIdx.x * 128;
  const int col0 = blockIdx.y * 128;
  const int lane = t & 63, lo = lane & 15, hi = lane >> 4;
  const int wv = t >> 6;
  const int wr = (wv >> 1) * 64, wc = (wv & 1) * 64;
  const int sx = lo & 3;

  f32x4 acc[4][4];
  #pragma unroll
  for (int i = 0; i < 4; ++i)
    #pragma unroll
    for (int j = 0; j < 4; ++j) acc[i][j] = (f32x4)0.0f;

  const int NT = K >> 5;

  auto stage = [&](int buf, int kt) {
    const int kof = kt * 32;
    #pragma unroll
    for (int c = 0; c < 2; ++c) {
      const int off = t * 16 + c * 4096;
      const int r = off >> 6;
      const int g = ((off >> 4) & 3) ^ (r & 3);
      GLDS16(A  + (size_t)(row0 + r) * K + (kof + g * 8), (u16*)As + buf * 4096 + (off >> 1));
      GLDS16(Bt + (size_t)(col0 + r) * K + (kof + g * 8), (u16*)Bs + buf * 4096 + (off >> 1));
    }
  };

  stage(0, 0);
  stage(1, 1);
  for (int kt = 0; kt < NT; ++kt) {
    const int cur = kt & 1;
    if (kt + 1 < NT) { VMCNT(4); } else { VMCNT(0); }
    BAR();
    bf16x8 af[4], bfr[4];
    #pragma unroll
    for (int mi = 0; mi < 4; ++mi) {
      const int row = wr + mi * 16 + lo;
      af[mi] = *(const bf16x8*)&As[cur][row * 32 + ((hi ^ sx) << 3)];
    }
    #pragma unroll
    for (int ni = 0; ni < 4; ++ni) {
      const int row = wc + ni * 16 + lo;
      bfr[ni] = *(const bf16x8*)&Bs[cur][row * 32 + ((hi ^ sx) << 3)];
    }
    #pragma unroll
    for (int mi = 0; mi < 4; ++mi)
      #pragma unroll
      for (int ni = 0; ni < 4; ++ni)
        acc[mi][ni] = __builtin_amdgcn_mfma_f32_16x16x32_bf16(af[mi], bfr[ni], acc[mi][ni], 0, 0, 0);
    BAR();
    if (kt + 2 < NT) stage(cur, kt + 2);
  }

  #pragma unroll
  for (int mi = 0; mi < 4; ++mi) {
    #pragma unroll
    for (int ni = 0; ni < 4; ++ni) {
      const int col = col0 + wc + ni * 16 + lo;
      const float bv = bias[col];
      #pragma unroll
      for (int r = 0; r < 4; ++r) {
        const int row = row0 + wr + mi * 16 + hi * 4 + r;
        C[(size_t)row * N + col] = f2bf(acc[mi][ni][r] + bv);
      }
    }
  }
}

// ---------------- out-proj NT GEMM: 128x64, BK=32, counted-vmcnt 2-phase (R9 best) ----------------
__global__ __launch_bounds__(256) void gemm_out64(
    const u16* __restrict__ A, const u16* __restrict__ Bt,
    const float* __restrict__ bias, float* __restrict__ C)
{
  constexpr int N = 1024, K = 1024;

  __shared__ u16 As[2][128 * 32];
  __shared__ u16 Bs[2][64 * 32];

  int id = blockIdx.y * gridDim.x + blockIdx.x;      // 0..511
  int wgid = (id & 7) * 64 + (id >> 3);
  const int row0 = (wgid >> 4) * 128;
  const int col0 = (wgid & 15) * 64;

  const int t = threadIdx.x;
  const int lane = t & 63, lo = lane & 15, hi = lane >> 4;
  const int wv = t >> 6;
  const int wr = (wv >> 1) * 64, wc = (wv & 1) * 32;
  const int sx = lo & 3;

  f32x4 acc[4][2];
  #pragma unroll
  for (int i = 0; i < 4; ++i)
    #pragma unroll
    for (int j = 0; j < 2; ++j) acc[i][j] = (f32x4)0.0f;

  auto stage = [&](int buf, int kt) {
    const int kof = kt * 32;
    #pragma unroll
    for (int c = 0; c < 2; ++c) {
      const int off = t * 16 + c * 4096;
      const int r = off >> 6;
      const int g = ((off >> 4) & 3) ^ (r & 3);
      GLDS16(A + (size_t)(row0 + r) * K + (kof + g * 8), (u16*)As + buf * 4096 + (off >> 1));
    }
    {
      const int off = t * 16;
      const int r = off >> 6;
      const int g = ((off >> 4) & 3) ^ (r & 3);
      GLDS16(Bt + (size_t)(col0 + r) * K + (kof + g * 8), (u16*)Bs + buf * 2048 + (off >> 1));
    }
  };

  stage(0, 0);
  stage(1, 1);
  for (int kt = 0; kt < (K >> 5); ++kt) {
    const int cur = kt & 1;
    if (kt + 1 < (K >> 5)) { VMCNT(3); } else { VMCNT(0); }
    BAR();
    bf16x8 af[4], bfr[2];
    #pragma unroll
    for (int mi = 0; mi < 4; ++mi) {
      const int row = wr + mi * 16 + lo;
      af[mi] = *(const bf16x8*)&As[cur][row * 32 + ((hi ^ sx) << 3)];
    }
    #pragma unroll
    for (int ni = 0; ni < 2; ++ni) {
      const int row = wc + ni * 16 + lo;
      bfr[ni] = *(const bf16x8*)&Bs[cur][row * 32 + ((hi ^ sx) << 3)];
    }
    #pragma unroll
    for (int mi = 0; mi < 4; ++mi)
      #pragma unroll
      for (int ni = 0; ni < 2; ++ni)
        acc[mi][ni] = __builtin_amdgcn_mfma_f32_16x16x32_bf16(af[mi], bfr[ni], acc[mi][ni], 0, 0, 0);
    BAR();
    if (kt + 2 < (K >> 5)) stage(cur, kt + 2);
  }

  #pragma unroll
  for (int mi = 0; mi < 4; ++mi) {
    #pragma unroll
    for (int ni = 0; ni < 2; ++ni) {
      const int col = col0 + wc + ni * 16 + lo;
      const float bv = bias[col];
      #pragma unroll
      for (int r = 0; r < 4; ++r) {
        const int row = row0 + wr + mi * 16 + hi * 4 + r;
        C[(size_t)row * N + col] = acc[mi][ni][r] + bv;
      }
    }
  }
}

// ---------------- attention: QBLK=128, 8 waves, swapped QK^T, in-register P ----------------
// Swapped S^T = mfma(K,Q): lane holds S[q=w0+lo][j=kstart+ni*16+hi*4+r] -> P stays
// in registers; PV A-fragment built via cvt_pk + 16 shfl (no Ps LDS). 32 KB LDS.
__device__ __forceinline__ int swzK(int row, int col) {
  int byte = (row << 7) + (col << 1);
  byte ^= (row & 7) << 4;
  return byte >> 1;
}
__device__ __forceinline__ int swzV(int d, int j) {
  int byte = (d << 7) + (j << 1);
  byte ^= ((d & 7) << 4) ^ (((d >> 4) & 3) << 5);
  return byte >> 1;
}

__global__ __launch_bounds__(512) void attn_win(const u16* __restrict__ Q,
                                                const u16* __restrict__ K,
                                                const u16* __restrict__ V,
                                                u16* __restrict__ O) {
  const int qt = blockIdx.x, h = blockIdx.y, b = blockIdx.z;
  const int q0 = qt * 128;
  const int t = threadIdx.x;
  const int wv = t >> 6, lane = t & 63, lo = lane & 15, hi = lane >> 4;

  __shared__ u16 Ks[2][64 * 64];   // 16 KiB
  __shared__ u16 Vt[2][64 * 64];   // 16 KiB

  const size_t base = ((size_t)b * S_LEN) * DMODEL + h * 64;
  const int w0 = q0 + wv * 16;      // this wave's 16-row strip

  // Q direct global->regs, pre-scaled by 1/8 (exact in bf16: exponent-only)
  bf16x8 qf[2];
  {
    const u16* qp = Q + base + (size_t)(w0 + lo) * DMODEL;
    u16x8 qa = *(const u16x8*)(qp + hi * 8);
    u16x8 qb = *(const u16x8*)(qp + 32 + hi * 8);
    union { u16x8 s; bf16x8 v; } ua, ub;
    #pragma unroll
    for (int e = 0; e < 8; ++e) {
      float fa = __builtin_bit_cast(float, (u32)qa[e] << 16) * 0.125f;
      float fb = __builtin_bit_cast(float, (u32)qb[e] << 16) * 0.125f;
      ua.s[e] = (u16)(__builtin_bit_cast(u32, fa) >> 16);
      ub.s[e] = (u16)(__builtin_bit_cast(u32, fb) >> 16);
    }
    qf[0] = ua.v; qf[1] = ub.v;
  }

  const int vrow = t >> 3;              // j in chunk (0..63)
  const int vc0  = (t & 7) * 8;         // d group (0..56)
  const int ktmin = max(0, (256 - q0) >> 6);

  u16x8 kra, vra;
  auto issue = [&](int kt) {
    const int jg = q0 - 256 + kt * 64 + vrow;
    if (jg >= 0) {
      kra = *(const u16x8*)(K + base + (size_t)jg * DMODEL + vc0);
      vra = *(const u16x8*)(V + base + (size_t)jg * DMODEL + vc0);
    } else { kra = (u16x8)0; vra = (u16x8)0; }
  };
  auto commit = [&](int buf) {
    *(u16x8*)&Ks[buf][swzK(vrow, vc0)] = kra;
    #pragma unroll
    for (int e = 0; e < 8; ++e)
      Vt[buf][swzV(vc0 + e, vrow)] = vra[e];
  };

  issue(ktmin);
  commit(0);
  __syncthreads();

  f32x4 oacc[4];
  #pragma unroll
  for (int i = 0; i < 4; ++i) oacc[i] = (f32x4)0.0f;
  float l = 0.f;

  const int sel = hi >> 1;
  const int lane_a = lo + ((lane & 16) << 1);   // lo + 32*(hi&1)

  int cur = 0;
  for (int kt = ktmin; kt < 6; ++kt) {
    const int kstart = q0 - 256 + kt * 64;
    if (kt < 5) issue(kt + 1);           // T14: next chunk's loads in flight

    const bool act = (kstart <= w0 + 15) && (kstart + 63 >= w0 - 255);
    if (act) {
      // S^T = mfma(K, Q): lane holds S[q=w0+lo][j=kstart+ni*16+hi*4+r]
      f32x4 sfr[4];
      #pragma unroll
      for (int ni = 0; ni < 4; ++ni) {
        sfr[ni] = (f32x4)0.0f;
        #pragma unroll
        for (int kq = 0; kq < 2; ++kq) {
          bf16x8 kf = *(const bf16x8*)&Ks[cur][swzK(ni * 16 + lo, kq * 32 + hi * 8)];
          sfr[ni] = __builtin_amdgcn_mfma_f32_16x16x32_bf16(kf, qf[kq], sfr[ni], 0, 0, 0);
        }
      }

      // mask + exp (no max subtraction); per-lane l partial (q = w0+lo)
      const int iq = w0 + lo;
      float pr[4][4];
      #pragma unroll
      for (int ni = 0; ni < 4; ++ni) {
        const int jb = kstart + ni * 16 + hi * 4;
        #pragma unroll
        for (int r = 0; r < 4; ++r) {
          const int j = jb + r;
          const bool ok = (j >= 0) & (j <= iq) & (iq - j < WIN);
          const float x = ok ? sfr[ni][r] : -1e30f;
          const float p = __expf(x);
          pr[ni][r] = p;
          l += p;
        }
      }

      // pack P -> bf16 pairs: w[ni][p] = {pr[ni][2p], pr[ni][2p+1]}
      u32 w[4][2];
      #pragma unroll
      for (int ni = 0; ni < 4; ++ni)
        #pragma unroll
        for (int p = 0; p < 2; ++p)
          asm("v_cvt_pk_bf16_f32 %0, %1, %2"
              : "=v"(w[ni][p]) : "v"(pr[ni][2 * p]), "v"(pr[ni][2 * p + 1]));

      // redistribute to PV A-fragment: pa[kp][e] = P[q=lo][j=kp*32+hi*8+e]
      bf16x8 pab[2];
      #pragma unroll
      for (int kp = 0; kp < 2; ++kp) {
        const u32 a0  = (u32)__shfl((int)w[2 * kp][0],     lane_a);
        const u32 a0b = (u32)__shfl((int)w[2 * kp + 1][0], lane_a);
        const u32 a1  = (u32)__shfl((int)w[2 * kp][1],     lane_a);
        const u32 a1b = (u32)__shfl((int)w[2 * kp + 1][1], lane_a);
        const u32 b0  = (u32)__shfl((int)w[2 * kp][0],     lane_a + 16);
        const u32 b0b = (u32)__shfl((int)w[2 * kp + 1][0], lane_a + 16);
        const u32 b1  = (u32)__shfl((int)w[2 * kp][1],     lane_a + 16);
        const u32 b1b = (u32)__shfl((int)w[2 * kp + 1][1], lane_a + 16);
        union { u32 ws[4]; bf16x8 v; } uu;
        uu.ws[0] = sel ? a0b : a0;
        uu.ws[1] = sel ? a1b : a1;
        uu.ws[2] = sel ? b0b : b0;
        uu.ws[3] = sel ? b1b : b1;
        pab[kp] = uu.v;
      }

      // PV: oacc[ni] += P * V
      #pragma unroll
      for (int ni = 0; ni < 4; ++ni) {
        #pragma unroll
        for (int kp = 0; kp < 2; ++kp) {
          bf16x8 vf = *(const bf16x8*)&Vt[cur][swzV(ni * 16 + lo, kp * 32 + hi * 8)];
          oacc[ni] = __builtin_amdgcn_mfma_f32_16x16x32_bf16(pab[kp], vf, oacc[ni], 0, 0, 0);
        }
      }
    }

    if (kt < 5) commit(cur ^ 1);
    __syncthreads();
    cur ^= 1;
  }

  // finalize l (per q=lo): sum the 4 hi-lanes sharing lo
  l += __shfl_xor(l, 16);
  l += __shfl_xor(l, 32);

  #pragma unroll
  for (int r = 0; r < 4; ++r) {
    const float lr = __shfl(l, hi * 4 + r);   // l for q-row = hi*4+r
    const float inv = 1.0f / lr;
    const int row = w0 + hi * 4 + r;
    #pragma unroll
    for (int ni = 0; ni < 4; ++ni)
      O[base + (size_t)row * DMODEL + ni * 16 + lo] = f2bf(oacc[ni][r] * inv);
  }
}

// ---------------- launch ----------------
extern "C" void kernel_launch(void* const* d_in, const int* in_sizes, int n_in,
                              void* d_out, int out_size, void* d_ws, size_t ws_size,
                              hipStream_t stream) {
  const float* x  = (const float*)d_in[0];
  const float* wq = (const float*)d_in[1];
  const float* bq = (const float*)d_in[2];
  const float* wk = (const float*)d_in[3];
  const float* bk = (const float*)d_in[4];
  const float* wvp = (const float*)d_in[5];
  const float* bv = (const float*)d_in[6];
  const float* wo = (const float*)d_in[7];
  const float* bo = (const float*)d_in[8];
  float* out = (float*)d_out;

  char* ws = (char*)d_ws;
  const size_t MB = 1024 * 1024;
  u16* xb  = (u16*)(ws);
  u16* wqb = (u16*)(ws + 8 * MB);
  u16* wkb = (u16*)(ws + 10 * MB);
  u16* wvb = (u16*)(ws + 12 * MB);
  u16* wob = (u16*)(ws + 14 * MB);
  u16* Qb  = (u16*)(ws + 16 * MB);
  u16* Kb  = (u16*)(ws + 24 * MB);
  u16* Vb  = (u16*)(ws + 32 * MB);
  u16* Ob  = (u16*)(ws + 40 * MB);   // ends at 48 MB

  cast_all<<<8192, 256, 0, stream>>>(x, wq, wk, wvp, wo, xb, wqb, wkb, wvb, wob);

  dim3 g1(4096 / 128, 1024 / 128, 3);
  gemm_nt<<<g1, 256, 0, stream>>>(xb, wqb, wkb, wvb, bq, bk, bv,
                                  Qb, Kb, Vb, 4096, 1024, 1024);

  attn_win<<<dim3(S_LEN / 128, NHEADS, 2), 512, 0, stream>>>(Qb, Kb, Vb, Ob);

  gemm_out64<<<dim3(32, 16), 256, 0, stream>>>(Ob, wob, bo, out);
}